// Round 4
// baseline (3586.858 us; speedup 1.0000x reference)
//
#include <hip/hip_runtime.h>
#include <hip/hip_bf16.h>

// AttenDecoder: B=64 T=32 S=64 E=128 H=256 V=32000.
// I/O fp32; compute bf16 MFMA (GEMMs) + fp32 VALU (recurrence).
// R4: k_recur rebuilt around TRANSPOSED bf16 weights: coalesced wave loads
// (contiguous 512B-1KB per instr), h broadcast from LDS, 512 thr (8 waves),
// explicit vector accumulators (no scratch), 6 barriers/step.

typedef __attribute__((ext_vector_type(8))) short  s8v;
typedef __attribute__((ext_vector_type(8))) __bf16 bf8v;
typedef __attribute__((ext_vector_type(4))) float  f4v;

#define DEV static __device__ __forceinline__

DEV ushort f2b(float f) {            // round-to-nearest-even fp32 -> bf16
  unsigned u = __float_as_uint(f);
  u += 0x7fffu + ((u >> 16) & 1u);
  return (ushort)(u >> 16);
}
DEV float b2fs(short s) { return __uint_as_float(((unsigned)(ushort)s) << 16); }

// ---------------------------------------------------------------- gather X
__global__ __launch_bounds__(256) void k_gather(
    const float* __restrict__ target, const float* __restrict__ inp,
    const float* __restrict__ posf,   const float* __restrict__ encs,
    ushort* __restrict__ X) {
  int tb = blockIdx.x; int t = tb >> 6, b = tb & 63;
  size_t xrow = (size_t)tb * 640;
  for (int c = threadIdx.x; c < 640; c += 256) {
    float v;
    if (c < 128)      v = target[((size_t)b * 32 + t) * 128 + c];
    else if (c < 256) v = posf[(size_t)b * 128 + (c - 128)];
    else if (c < 512) v = encs[(size_t)b * 256 + (c - 256)];
    else              v = inp[((size_t)b * 32 + t) * 128 + (c - 512)];
    X[xrow + c] = f2b(v);
  }
}

// --------------------------------- fp32 -> bf16 TRANSPOSED weight convert
// in[R][C] fp32 -> out[C][R] bf16, 32x32 LDS tiles, coalesced both sides.
__global__ __launch_bounds__(256) void k_cvt_t(
    const float* __restrict__ in, ushort* __restrict__ out, int R, int C) {
  __shared__ float tile[32][33];
  const int c0 = blockIdx.x * 32, r0 = blockIdx.y * 32;
  const int tx = threadIdx.x & 31, ty = threadIdx.x >> 5;
#pragma unroll
  for (int i = 0; i < 32; i += 8)
    tile[ty + i][tx] = in[(size_t)(r0 + ty + i) * C + c0 + tx];
  __syncthreads();
#pragma unroll
  for (int i = 0; i < 32; i += 8)
    out[(size_t)(c0 + ty + i) * R + r0 + tx] = f2b(tile[tx][ty + i]);
}

// ------------------------------------------------- MFMA GEMM, B^T layout
template <bool RELU>
__global__ __launch_bounds__(256) void k_gemm_bt(
    const ushort* __restrict__ A, const float* __restrict__ B,
    const float* __restrict__ bias, float* __restrict__ Out,
    int N, int K) {
  __shared__ __align__(16) ushort As[128 * 40];
  __shared__ __align__(16) ushort Bs[128 * 40];
  const int m0 = blockIdx.x * 128, n0 = blockIdx.y * 128;
  const int tid = threadIdx.x;
  const int lane = tid & 63, wv = tid >> 6;
  const int wm = (wv >> 1) * 64, wn = (wv & 1) * 64;
  const int fr = lane & 15, fq = lane >> 4;
  const int srow = tid >> 2, scol = (tid & 3) * 8;
  f4v acc[4][4];
#pragma unroll
  for (int i = 0; i < 4; ++i)
#pragma unroll
    for (int j = 0; j < 4; ++j) acc[i][j] = {0.f, 0.f, 0.f, 0.f};
  const ushort* ag = A + (size_t)(m0 + srow) * K + scol;
  const float*  bg = B + (size_t)(n0 + srow) * K + scol;
  for (int k0 = 0; k0 < K; k0 += 32) {
    s8v a0 = *(const s8v*)(ag + k0);
    s8v a1 = *(const s8v*)(ag + k0 + (size_t)64 * K);
    f4v b00 = *(const f4v*)(bg + k0);
    f4v b01 = *(const f4v*)(bg + k0 + 4);
    f4v b10 = *(const f4v*)(bg + k0 + (size_t)64 * K);
    f4v b11 = *(const f4v*)(bg + k0 + (size_t)64 * K + 4);
    s8v b0, b1;
#pragma unroll
    for (int u = 0; u < 4; ++u) {
      b0[u]     = (short)f2b(b00[u]);
      b0[u + 4] = (short)f2b(b01[u]);
      b1[u]     = (short)f2b(b10[u]);
      b1[u + 4] = (short)f2b(b11[u]);
    }
    __syncthreads();
    *(s8v*)&As[srow * 40 + scol] = a0;
    *(s8v*)&As[(srow + 64) * 40 + scol] = a1;
    *(s8v*)&Bs[srow * 40 + scol] = b0;
    *(s8v*)&Bs[(srow + 64) * 40 + scol] = b1;
    __syncthreads();
    bf8v af[4], bfr[4];
#pragma unroll
    for (int i = 0; i < 4; ++i)
      af[i] = *(const bf8v*)&As[(wm + i * 16 + fr) * 40 + fq * 8];
#pragma unroll
    for (int j = 0; j < 4; ++j)
      bfr[j] = *(const bf8v*)&Bs[(wn + j * 16 + fr) * 40 + fq * 8];
#pragma unroll
    for (int i = 0; i < 4; ++i)
#pragma unroll
      for (int j = 0; j < 4; ++j)
        acc[i][j] = __builtin_amdgcn_mfma_f32_16x16x32_bf16(af[i], bfr[j],
                                                            acc[i][j], 0, 0, 0);
  }
  float bj[4];
#pragma unroll
  for (int j = 0; j < 4; ++j) bj[j] = bias[n0 + wn + j * 16 + fr];
#pragma unroll
  for (int i = 0; i < 4; ++i) {
#pragma unroll
    for (int j = 0; j < 4; ++j) {
#pragma unroll
      for (int r = 0; r < 4; ++r) {
        int gm = m0 + wm + i * 16 + fq * 4 + r;
        int gn = n0 + wn + j * 16 + fr;
        float v = acc[i][j][r] + bj[j];
        if (RELU) v = fmaxf(v, 0.f);
        Out[(size_t)gm * N + gn] = v;
      }
    }
  }
}

// -------------------------------------------------------- recurrence (R4)
// One block (512 thr, 8 waves) per batch element b.  Weights TRANSPOSED
// bf16: WhhT[k][768], WinT[k][512] -> wave loads contiguous; h broadcast.
__global__ __launch_bounds__(512) void k_recur(
    const float* __restrict__ gi_all,   // [32*64][768] fp32 (includes b_ih)
    const float* __restrict__ eo,       // [64][64][512] fp32
    const ushort* __restrict__ WhhT,    // [256 k][768 o] bf16
    const float* __restrict__ bhh,      // [768]
    const ushort* __restrict__ WinT,    // [256 k][512 o] bf16
    const float* __restrict__ Winb,     // [512]
    ushort* __restrict__ feat,          // [32*64][768] bf16 (GEMM A)
    float* __restrict__ hs_out) {       // [64][256] fp32 (d_out base)
  const int b = blockIdx.x, tid = threadIdx.x;
  __shared__ __align__(16) float h[2][256];
  __shared__ __align__(16) float gis[768];
  __shared__ __align__(16) float partb[16 * 768];   // gh: [16p][768o]; q: [8p][512o]
  __shared__ __align__(16) float qv[512];
  __shared__ float attns[64];
  __shared__ float score[64];
  const float* eoB = eo + (size_t)b * 32768;

  float bhr = 0.f, bhz = 0.f, bhn = 0.f;
  if (tid < 256) { bhr = bhh[tid]; bhz = bhh[tid + 256]; bhn = bhh[tid + 512]; }
  const float qb = Winb[tid < 512 ? tid : 0];
  if (tid < 256) { h[0][tid] = 0.f; }
  __syncthreads();

  // gh mapping: 8 consecutive cols per thread per gate; 16 k-slices of 16.
  const int cg = (tid & 31) * 8, pg = tid >> 5;     // cols cg..cg+7, k in [16pg,16pg+16)
  // q mapping: 8 cols of 512; 8 k-slices of 32.
  const int cq = (tid & 63) * 8, pq = tid >> 6;     // k in [32pq,32pq+32)
  // attn mapping: 8 threads per s.
  const int sa = tid >> 3, ga = tid & 7;

  for (int st = 0; st < 32; ++st) {
    const float* hc = h[st & 1];
    float* hn = h[(st & 1) ^ 1];
    const float* gi_row = gi_all + ((size_t)st * 64 + b) * 768;
    float gp0 = gi_row[tid];
    float gp1 = (tid < 256) ? gi_row[512 + tid] : 0.f;

    // ---- gh partials: gates {r,z,n}, cols cg..cg+7, k-slice pg
    {
      f4v ar0 = {0,0,0,0}, ar1 = {0,0,0,0};
      f4v az0 = {0,0,0,0}, az1 = {0,0,0,0};
      f4v an0 = {0,0,0,0}, an1 = {0,0,0,0};
      const ushort* wbase = WhhT + (size_t)(16 * pg) * 768 + cg;
#pragma unroll
      for (int kk = 0; kk < 16; ++kk) {
        const ushort* wrow = wbase + (size_t)kk * 768;
        s8v wr = *(const s8v*)(wrow);
        s8v wz = *(const s8v*)(wrow + 256);
        s8v wn = *(const s8v*)(wrow + 512);
        float hk = hc[16 * pg + kk];
        ar0.x = fmaf(hk, b2fs(wr[0]), ar0.x); ar0.y = fmaf(hk, b2fs(wr[1]), ar0.y);
        ar0.z = fmaf(hk, b2fs(wr[2]), ar0.z); ar0.w = fmaf(hk, b2fs(wr[3]), ar0.w);
        ar1.x = fmaf(hk, b2fs(wr[4]), ar1.x); ar1.y = fmaf(hk, b2fs(wr[5]), ar1.y);
        ar1.z = fmaf(hk, b2fs(wr[6]), ar1.z); ar1.w = fmaf(hk, b2fs(wr[7]), ar1.w);
        az0.x = fmaf(hk, b2fs(wz[0]), az0.x); az0.y = fmaf(hk, b2fs(wz[1]), az0.y);
        az0.z = fmaf(hk, b2fs(wz[2]), az0.z); az0.w = fmaf(hk, b2fs(wz[3]), az0.w);
        az1.x = fmaf(hk, b2fs(wz[4]), az1.x); az1.y = fmaf(hk, b2fs(wz[5]), az1.y);
        az1.z = fmaf(hk, b2fs(wz[6]), az1.z); az1.w = fmaf(hk, b2fs(wz[7]), az1.w);
        an0.x = fmaf(hk, b2fs(wn[0]), an0.x); an0.y = fmaf(hk, b2fs(wn[1]), an0.y);
        an0.z = fmaf(hk, b2fs(wn[2]), an0.z); an0.w = fmaf(hk, b2fs(wn[3]), an0.w);
        an1.x = fmaf(hk, b2fs(wn[4]), an1.x); an1.y = fmaf(hk, b2fs(wn[5]), an1.y);
        an1.z = fmaf(hk, b2fs(wn[6]), an1.z); an1.w = fmaf(hk, b2fs(wn[7]), an1.w);
      }
      float* pr = &partb[pg * 768];
      *(f4v*)(pr + cg) = ar0;       *(f4v*)(pr + cg + 4) = ar1;
      *(f4v*)(pr + 256 + cg) = az0; *(f4v*)(pr + 256 + cg + 4) = az1;
      *(f4v*)(pr + 512 + cg) = an0; *(f4v*)(pr + 512 + cg + 4) = an1;
    }
    gis[tid] = gp0;
    if (tid < 256) gis[512 + tid] = gp1;
    __syncthreads();                                        // (1)
    // ---- gates + h update (threads 0..255); also feat h-part
    if (tid < 256) {
      float ar = bhr, az = bhz, an = bhn;
#pragma unroll
      for (int p = 0; p < 16; ++p) {
        ar += partb[p * 768 + tid];
        az += partb[p * 768 + 256 + tid];
        an += partb[p * 768 + 512 + tid];
      }
      float r = 1.f / (1.f + __expf(-(gis[tid] + ar)));
      float z = 1.f / (1.f + __expf(-(gis[tid + 256] + az)));
      float e2 = __expf(2.f * (gis[tid + 512] + r * an));   // tanh, inf-safe
      float n = 1.f - 2.f / (e2 + 1.f);
      float hnew = (1.f - z) * n + z * hc[tid];
      hn[tid] = hnew;
      feat[((size_t)st * 64 + b) * 768 + 512 + tid] = f2b(hnew);
      if (st == 31) hs_out[(size_t)b * 256 + tid] = hnew;
    }
    __syncthreads();                                        // (2)
    // ---- q partials: cols cq..cq+7, k-slice pq
    {
      f4v a0 = {0,0,0,0}, a1 = {0,0,0,0};
      const ushort* wbase = WinT + (size_t)(32 * pq) * 512 + cq;
#pragma unroll
      for (int kk = 0; kk < 32; ++kk) {
        s8v w8 = *(const s8v*)(wbase + (size_t)kk * 512);
        float hk = hn[32 * pq + kk];
        a0.x = fmaf(hk, b2fs(w8[0]), a0.x); a0.y = fmaf(hk, b2fs(w8[1]), a0.y);
        a0.z = fmaf(hk, b2fs(w8[2]), a0.z); a0.w = fmaf(hk, b2fs(w8[3]), a0.w);
        a1.x = fmaf(hk, b2fs(w8[4]), a1.x); a1.y = fmaf(hk, b2fs(w8[5]), a1.y);
        a1.z = fmaf(hk, b2fs(w8[6]), a1.z); a1.w = fmaf(hk, b2fs(w8[7]), a1.w);
      }
      float* pr = &partb[pq * 512];
      *(f4v*)(pr + cq) = a0; *(f4v*)(pr + cq + 4) = a1;
    }
    __syncthreads();                                        // (3)
    {
      float s = qb;
#pragma unroll
      for (int p = 0; p < 8; ++p) s += partb[p * 512 + tid];
      qv[tid] = s;
    }
    __syncthreads();                                        // (4)
    // ---- attn: 8 threads per s
    {
      const float* ep = eoB + sa * 512 + ga * 4;
      const float* qp = &qv[ga * 4];
      float aa = 0.f;
#pragma unroll
      for (int j = 0; j < 16; ++j) {
        f4v e4 = *(const f4v*)(ep + j * 32);
        f4v q4 = *(const f4v*)(qp + j * 32);
        aa = fmaf(e4.x, q4.x, aa); aa = fmaf(e4.y, q4.y, aa);
        aa = fmaf(e4.z, q4.z, aa); aa = fmaf(e4.w, q4.w, aa);
      }
      aa += __shfl_xor(aa, 4); aa += __shfl_xor(aa, 2); aa += __shfl_xor(aa, 1);
      if (ga == 0) attns[sa] = aa;
    }
    __syncthreads();                                        // (5)
    if (tid < 64) {                                         // softmax (wave 0)
      float a = attns[tid], m = a;
#pragma unroll
      for (int off = 32; off > 0; off >>= 1) m = fmaxf(m, __shfl_xor(m, off));
      float e = __expf(a - m), ss = e;
#pragma unroll
      for (int off = 32; off > 0; off >>= 1) ss += __shfl_xor(ss, off);
      score[tid] = e / ss;
    }
    __syncthreads();                                        // (6)
    // ---- h_star[tid] = sum_s score[s]*eo[b,s,tid]; feat h_star part
    {
      float a = 0.f;
      const float* ep = eoB + tid;
#pragma unroll 8
      for (int s2 = 0; s2 < 64; ++s2) a = fmaf(score[s2], ep[(size_t)s2 * 512], a);
      feat[((size_t)st * 64 + b) * 768 + tid] = f2b(a);
    }
    // no barrier needed: next-step writes to partb/gis happen after barrier(1)'
  }
}

// ----------------------------------------------- in-place log_softmax (fp32)
__global__ __launch_bounds__(256) void k_logsm(float* __restrict__ out) {
  float* p = out + (size_t)blockIdx.x * 32000;
  const int t = threadIdx.x;
  __shared__ float red[4];
  float m = 0.f;  // relu'd values are >= 0
  for (int c = t; c < 4000; c += 256) {
    f4v a = *(const f4v*)(p + (size_t)c * 8);
    f4v b = *(const f4v*)(p + (size_t)c * 8 + 4);
    m = fmaxf(m, fmaxf(fmaxf(a.x, a.y), fmaxf(a.z, a.w)));
    m = fmaxf(m, fmaxf(fmaxf(b.x, b.y), fmaxf(b.z, b.w)));
  }
#pragma unroll
  for (int off = 32; off > 0; off >>= 1) m = fmaxf(m, __shfl_xor(m, off));
  if ((t & 63) == 0) red[t >> 6] = m;
  __syncthreads();
  m = fmaxf(fmaxf(red[0], red[1]), fmaxf(red[2], red[3]));
  float s = 0.f;
  for (int c = t; c < 4000; c += 256) {
    f4v a = *(const f4v*)(p + (size_t)c * 8);
    f4v b = *(const f4v*)(p + (size_t)c * 8 + 4);
    s += __expf(a.x - m) + __expf(a.y - m) + __expf(a.z - m) + __expf(a.w - m);
    s += __expf(b.x - m) + __expf(b.y - m) + __expf(b.z - m) + __expf(b.w - m);
  }
#pragma unroll
  for (int off = 32; off > 0; off >>= 1) s += __shfl_xor(s, off);
  __syncthreads();
  if ((t & 63) == 0) red[t >> 6] = s;
  __syncthreads();
  s = red[0] + red[1] + red[2] + red[3];
  const float L = m + logf(s);
  for (int c = t; c < 4000; c += 256) {
    f4v a = *(const f4v*)(p + (size_t)c * 8);
    f4v b = *(const f4v*)(p + (size_t)c * 8 + 4);
    a.x -= L; a.y -= L; a.z -= L; a.w -= L;
    b.x -= L; b.y -= L; b.z -= L; b.w -= L;
    *(f4v*)(p + (size_t)c * 8) = a;
    *(f4v*)(p + (size_t)c * 8 + 4) = b;
  }
}

extern "C" void kernel_launch(void* const* d_in, const int* in_sizes, int n_in,
                              void* d_out, int out_size, void* d_ws, size_t ws_size,
                              hipStream_t stream) {
  (void)in_sizes; (void)n_in; (void)out_size; (void)ws_size;
  const float* target = (const float*)d_in[0];
  const float* inp    = (const float*)d_in[1];
  const float* posf   = (const float*)d_in[2];
  const float* encs   = (const float*)d_in[3];
  const float* enco   = (const float*)d_in[4];
  const float* Wih    = (const float*)d_in[5];
  const float* Whh    = (const float*)d_in[6];
  const float* bih    = (const float*)d_in[7];
  const float* bhh    = (const float*)d_in[8];
  const float* Winw   = (const float*)d_in[9];
  const float* Winb   = (const float*)d_in[10];
  const float* Woutw  = (const float*)d_in[11];
  const float* Woutb  = (const float*)d_in[12];

  char* ws = (char*)d_ws;
  ushort* X     = (ushort*)(ws);              // 2048*640  bf16 = 0x280000
  float*  gi    = (float*)(ws + 0x280000);    // 2048*768  fp32 = 0x600000
  ushort* feat  = (ushort*)(ws + 0x880000);   // 2048*768  bf16 = 0x300000
  ushort* WhhT  = (ushort*)(ws + 0xB80000);   // 256*768   bf16 = 0x60000
  ushort* WinT  = (ushort*)(ws + 0xBE0000);   // 256*512   bf16 = 0x40000
  float* hs     = (float*)d_out;              // [16384 hs][2048*32000 logits]
  float* logits = hs + 16384;

  k_cvt_t<<<dim3(8, 24), 256, 0, stream>>>(Whh, WhhT, 768, 256);
  k_cvt_t<<<dim3(8, 16), 256, 0, stream>>>(Winw, WinT, 512, 256);
  k_gather<<<2048, 256, 0, stream>>>(target, inp, posf, encs, X);
  k_gemm_bt<false><<<dim3(16, 6), 256, 0, stream>>>(X, Wih, bih, gi, 768, 640);
  k_recur<<<64, 512, 0, stream>>>(gi, enco, WhhT, bhh, WinT, Winb, feat, hs);
  k_gemm_bt<true><<<dim3(16, 250), 256, 0, stream>>>(feat, Woutw, Woutb, logits,
                                                     32000, 768);
  k_logsm<<<2048, 256, 0, stream>>>(logits);
}